// Round 7
// baseline (405.260 us; speedup 1.0000x reference)
//
#include <hip/hip_runtime.h>

typedef __bf16 bf16;
typedef __bf16 bf16x4 __attribute__((ext_vector_type(4)));
typedef __bf16 bf16x8 __attribute__((ext_vector_type(8)));
typedef float f32x4 __attribute__((ext_vector_type(4)));

#define SEQ 1024
#define EMB 1024
#define NH 16
#define HD 64
#define M2 2047   // 2*MAX_POS - 1

// ---------------------------------------------------------------------------
// Kernel 1 (R2 structure) with REP amplification loop for profiling rank.
// ---------------------------------------------------------------------------
template <int REP>
__global__ __launch_bounds__(256) void gemm1_rep_kernel(const float* __restrict__ posEmb,
                                                        const float* __restrict__ W,
                                                        bf16* __restrict__ P) {
  __shared__ bf16 As[64][72];
  __shared__ bf16 Bs[64][72];
  const int tid  = threadIdx.x;
  const int lane = tid & 63;
  const int wave = tid >> 6;
  const int wr = wave >> 1, wc = wave & 1;
  const int m0 = blockIdx.y * 64;
  const int n0 = blockIdx.x * 64;

#pragma clang loop unroll(disable)
  for (int rep = 0; rep < REP; ++rep) {
    f32x4 acc[2][2] = {};

    for (int k0 = 0; k0 < EMB; k0 += 64) {
      {
        const int row = tid >> 2;
        const int c0  = (tid & 3) * 16;
        int g = m0 + row;
        if (g > M2 - 1) g = M2 - 1;
        const float4* src = reinterpret_cast<const float4*>(posEmb + (size_t)g * EMB + k0 + c0);
        #pragma unroll
        for (int i = 0; i < 4; ++i) {
          float4 v = src[i];
          bf16x4 bb = { (bf16)v.x, (bf16)v.y, (bf16)v.z, (bf16)v.w };
          *reinterpret_cast<bf16x4*>(&As[row][c0 + 4 * i]) = bb;
        }
      }
      {
        const int n  = tid & 63;
        const int kg = tid >> 6;
        #pragma unroll
        for (int u = 0; u < 4; ++u) {
          bf16x4 bb;
          #pragma unroll
          for (int e = 0; e < 4; ++e) {
            int k = kg * 16 + u * 4 + e;
            bb[e] = (bf16)W[(size_t)(k0 + k) * EMB + n0 + n];
          }
          *reinterpret_cast<bf16x4*>(&Bs[n][kg * 16 + u * 4]) = bb;
        }
      }
      __syncthreads();
      #pragma unroll
      for (int ks = 0; ks < 2; ++ks) {
        bf16x8 a[2], b[2];
        #pragma unroll
        for (int x = 0; x < 2; ++x) {
          a[x] = *reinterpret_cast<const bf16x8*>(&As[wr * 32 + x * 16 + (lane & 15)][ks * 32 + 8 * (lane >> 4)]);
          b[x] = *reinterpret_cast<const bf16x8*>(&Bs[wc * 32 + x * 16 + (lane & 15)][ks * 32 + 8 * (lane >> 4)]);
        }
        #pragma unroll
        for (int x = 0; x < 2; ++x)
          #pragma unroll
          for (int y = 0; y < 2; ++y)
            acc[x][y] = __builtin_amdgcn_mfma_f32_16x16x32_bf16(a[x], b[y], acc[x][y], 0, 0, 0);
      }
      __syncthreads();
    }

    #pragma unroll
    for (int x = 0; x < 2; ++x)
      #pragma unroll
      for (int y = 0; y < 2; ++y)
        #pragma unroll
        for (int r = 0; r < 4; ++r) {
          int row = m0 + wr * 32 + x * 16 + (lane >> 4) * 4 + r;
          int col = n0 + wc * 32 + y * 16 + (lane & 15);
          P[(size_t)row * EMB + col] = (bf16)acc[x][y][r];
        }
    __syncthreads();
  }
}

// ---------------------------------------------------------------------------
// Kernel 2 (R2 structure), template VARIANT ablation + REP amplification.
//   V=0 FULL, V=1 NOSTORE (staging+MFMA, acc kept live, no epilogue),
//   V=2 STOREONLY (loop skeleton + epilogue with opaque values).
// ---------------------------------------------------------------------------
template <int V, int REP>
__global__ __launch_bounds__(256) void band2_var_kernel(const float* __restrict__ q,
                                                        const bf16* __restrict__ P,
                                                        float* __restrict__ out) {
  __shared__ bf16 Pbuf[2][64 * 64];
  const int tid  = threadIdx.x;
  const int lane = tid & 63;
  const int wave = tid >> 6;
  const int wr = wave >> 1, wc = wave & 1;

  const int i0 = blockIdx.x * 64;
  const int hb = blockIdx.y;
  const int h  = hb >> 1;
  const int b  = hb & 1;

  bf16x8 a[2][2];
  {
    const float* qbase = q + ((size_t)(h * (2 * SEQ) + b * SEQ)) * HD;
    const int row = i0 + wr * 32 + (lane & 15);
    const int kof = 8 * (lane >> 4);
    #pragma unroll
    for (int x = 0; x < 2; ++x)
      #pragma unroll
      for (int ks = 0; ks < 2; ++ks) {
        const float* src = qbase + (size_t)(row + x * 16) * HD + ks * 32 + kof;
        float4 v0 = *reinterpret_cast<const float4*>(src);
        float4 v1 = *reinterpret_cast<const float4*>(src + 4);
        bf16x8 f = { (bf16)v0.x, (bf16)v0.y, (bf16)v0.z, (bf16)v0.w,
                     (bf16)v1.x, (bf16)v1.y, (bf16)v1.z, (bf16)v1.w };
        a[x][ks] = f;
      }
  }

  const int m_base = (SEQ - 1) - (i0 + 63);
  const int tb = blockIdx.z * 9;
  const int te = (blockIdx.z == 0) ? 9 : 17;

  auto STAGE = [&](int bi, int t) {
    const int m0 = m_base + t * 64;
    const char* Pb = reinterpret_cast<const char*>(P);
    #pragma unroll
    for (int i = 0; i < 2; ++i) {
      int s   = wave * 128 + i * 64 + lane;
      int row = s >> 3;
      int cs  = s & 7;
      int cd  = cs ^ (row & 7);
      const void* g = Pb + ((size_t)(m0 + row) * EMB + h * HD) * 2 + cd * 16;
      char* l = reinterpret_cast<char*>(&Pbuf[bi][0]) + (wave * 128 + i * 64) * 16;
      __builtin_amdgcn_global_load_lds(
          (const __attribute__((address_space(1))) void*)g,
          (__attribute__((address_space(3))) void*)l, 16, 0, 0);
    }
  };

  const size_t outbase = (size_t)hb << 20;

#pragma clang loop unroll(disable)
  for (int rep = 0; rep < REP; ++rep) {
    if (V != 2) {
      STAGE(0, tb);
    }
    __syncthreads();

    int cur = 0;
    for (int t = tb; t < te; ++t) {
      if (V != 2 && t + 1 < te) STAGE(cur ^ 1, t + 1);

      f32x4 acc[2][2] = {};
      if (V != 2) {
        const char* buf = reinterpret_cast<const char*>(&Pbuf[cur][0]);
        #pragma unroll
        for (int ks = 0; ks < 2; ++ks) {
          bf16x8 bb[2];
          #pragma unroll
          for (int y = 0; y < 2; ++y) {
            int mrow  = wc * 32 + y * 16 + (lane & 15);
            int chunk = ks * 4 + (lane >> 4);
            int sw    = chunk ^ (mrow & 7);
            bb[y] = *reinterpret_cast<const bf16x8*>(buf + mrow * 128 + sw * 16);
          }
          #pragma unroll
          for (int x = 0; x < 2; ++x)
            #pragma unroll
            for (int y = 0; y < 2; ++y)
              acc[x][y] = __builtin_amdgcn_mfma_f32_16x16x32_bf16(a[x][ks], bb[y], acc[x][y], 0, 0, 0);
        }
      }

      if (V == 1) {
        // keep MFMA results live without storing (rule #17: prevent DCE)
        #pragma unroll
        for (int x = 0; x < 2; ++x)
          #pragma unroll
          for (int y = 0; y < 2; ++y)
            asm volatile("" :: "v"(acc[x][y][0]), "v"(acc[x][y][1]),
                               "v"(acc[x][y][2]), "v"(acc[x][y][3]));
      } else {
        if (V == 2) {
          // opaque values so nothing upstream is needed, stores can't fold
          #pragma unroll
          for (int x = 0; x < 2; ++x)
            #pragma unroll
            for (int y = 0; y < 2; ++y)
              asm volatile("" : "+v"(acc[x][y][0]), "+v"(acc[x][y][1]),
                                 "+v"(acc[x][y][2]), "+v"(acc[x][y][3]));
        }
        const int m0 = m_base + t * 64;
        #pragma unroll
        for (int x = 0; x < 2; ++x)
          #pragma unroll
          for (int y = 0; y < 2; ++y)
            #pragma unroll
            for (int r = 0; r < 4; ++r) {
              int i = i0 + wr * 32 + x * 16 + (lane >> 4) * 4 + r;
              int m = m0 + wc * 32 + y * 16 + (lane & 15);
              int j = m - (SEQ - 1) + i;
              if ((unsigned)j < SEQ)
                out[outbase + (size_t)i * SEQ + j] = acc[x][y][r];
            }
      }

      __syncthreads();
      cur ^= 1;
    }
  }
}

extern "C" void kernel_launch(void* const* d_in, const int* in_sizes, int n_in,
                              void* d_out, int out_size, void* d_ws, size_t ws_size,
                              hipStream_t stream) {
  const float* query  = (const float*)d_in[0];   // [2,16,1024,64]
  const float* posEmb = (const float*)d_in[1];   // [2047,1024]
  const float* W      = (const float*)d_in[2];   // [1024,1024]
  float* out = (float*)d_out;                    // [2,16,1024,1024]
  bf16* P = (bf16*)d_ws;                         // [2048][1024] bf16 = 4 MB

  // --- PROFILING ROUND: amplified dispatches so rocprof top-5 shows OUR kernels.
  // Order matters: ablated variants write garbage; the FULL variant runs LAST
  // and overwrites everything with correct values (validated by harness).
  gemm1_rep_kernel<6><<<dim3(16, 32), 256, 0, stream>>>(posEmb, W, P);
  band2_var_kernel<2, 6><<<dim3(16, 32, 2), 256, 0, stream>>>(query, P, out);  // STOREONLY
  band2_var_kernel<1, 8><<<dim3(16, 32, 2), 256, 0, stream>>>(query, P, out);  // NOSTORE
  band2_var_kernel<0, 4><<<dim3(16, 32, 2), 256, 0, stream>>>(query, P, out);  // FULL (correct)
}

// Round 8
// 65.623 us; speedup vs baseline: 6.1756x; 6.1756x over previous
//
#include <hip/hip_runtime.h>

typedef __bf16 bf16;
typedef __bf16 bf16x4 __attribute__((ext_vector_type(4)));
typedef __bf16 bf16x8 __attribute__((ext_vector_type(8)));
typedef float f32x4 __attribute__((ext_vector_type(4)));

#define SEQ 1024
#define EMB 1024
#define NH 16
#define HD 64
#define M2 2047   // 2*MAX_POS - 1

// ---------------------------------------------------------------------------
// Kernel 1 (R2 version, unchanged): P[2048][1024] (bf16) = gather(posEmb) @ W
// ---------------------------------------------------------------------------
__global__ __launch_bounds__(256) void gemm1_kernel(const float* __restrict__ posEmb,
                                                    const float* __restrict__ W,
                                                    bf16* __restrict__ P) {
  __shared__ bf16 As[64][72];
  __shared__ bf16 Bs[64][72];
  const int tid  = threadIdx.x;
  const int lane = tid & 63;
  const int wave = tid >> 6;
  const int wr = wave >> 1, wc = wave & 1;
  const int m0 = blockIdx.y * 64;
  const int n0 = blockIdx.x * 64;

  f32x4 acc[2][2] = {};

  for (int k0 = 0; k0 < EMB; k0 += 64) {
    {
      const int row = tid >> 2;
      const int c0  = (tid & 3) * 16;
      int g = m0 + row;
      if (g > M2 - 1) g = M2 - 1;
      const float4* src = reinterpret_cast<const float4*>(posEmb + (size_t)g * EMB + k0 + c0);
      #pragma unroll
      for (int i = 0; i < 4; ++i) {
        float4 v = src[i];
        bf16x4 bb = { (bf16)v.x, (bf16)v.y, (bf16)v.z, (bf16)v.w };
        *reinterpret_cast<bf16x4*>(&As[row][c0 + 4 * i]) = bb;
      }
    }
    {
      const int n  = tid & 63;
      const int kg = tid >> 6;
      #pragma unroll
      for (int u = 0; u < 4; ++u) {
        bf16x4 bb;
        #pragma unroll
        for (int e = 0; e < 4; ++e) {
          int k = kg * 16 + u * 4 + e;
          bb[e] = (bf16)W[(size_t)(k0 + k) * EMB + n0 + n];
        }
        *reinterpret_cast<bf16x4*>(&Bs[n][kg * 16 + u * 4]) = bb;
      }
    }
    __syncthreads();
    #pragma unroll
    for (int ks = 0; ks < 2; ++ks) {
      bf16x8 a[2], b[2];
      #pragma unroll
      for (int x = 0; x < 2; ++x) {
        a[x] = *reinterpret_cast<const bf16x8*>(&As[wr * 32 + x * 16 + (lane & 15)][ks * 32 + 8 * (lane >> 4)]);
        b[x] = *reinterpret_cast<const bf16x8*>(&Bs[wc * 32 + x * 16 + (lane & 15)][ks * 32 + 8 * (lane >> 4)]);
      }
      #pragma unroll
      for (int x = 0; x < 2; ++x)
        #pragma unroll
        for (int y = 0; y < 2; ++y)
          acc[x][y] = __builtin_amdgcn_mfma_f32_16x16x32_bf16(a[x], b[y], acc[x][y], 0, 0, 0);
    }
    __syncthreads();
  }

  #pragma unroll
  for (int x = 0; x < 2; ++x)
    #pragma unroll
    for (int y = 0; y < 2; ++y)
      #pragma unroll
      for (int r = 0; r < 4; ++r) {
        int row = m0 + wr * 32 + x * 16 + (lane >> 4) * 4 + r;
        int col = n0 + wc * 32 + y * 16 + (lane & 15);
        P[(size_t)row * EMB + col] = (bf16)acc[x][y][r];
      }
}

// ---------------------------------------------------------------------------
// Kernel 2 (band2c, NO-LDS / NO-BARRIER): band GEMM, m-loop in-block.
//   B-fragments (P tile) read DIRECTLY from global per tile — P is 4 MB and
//   L2/L3-resident (R7: FETCH ~13 KB), so these are cache hits. No __shared__,
//   no __syncthreads, no vmcnt(0) serialization: waves stream stores of tile t
//   while loading/computing tile t+1. Q in registers (loaded once).
// ---------------------------------------------------------------------------
__global__ __launch_bounds__(256) void band2c_kernel(const float* __restrict__ q,
                                                     const bf16* __restrict__ P,
                                                     float* __restrict__ out) {
  const int tid  = threadIdx.x;
  const int lane = tid & 63;
  const int wave = tid >> 6;
  const int wr = wave >> 1, wc = wave & 1;

  const int i0 = blockIdx.x * 64;
  const int hb = blockIdx.y;          // h*2 + b
  const int h  = hb >> 1;
  const int b  = hb & 1;

  // ---- Q fragments: direct global f32 -> bf16x8 registers (as R2).
  bf16x8 a[2][2];
  {
    const float* qbase = q + ((size_t)(h * (2 * SEQ) + b * SEQ)) * HD;
    const int row = i0 + wr * 32 + (lane & 15);
    const int kof = 8 * (lane >> 4);
    #pragma unroll
    for (int x = 0; x < 2; ++x)
      #pragma unroll
      for (int ks = 0; ks < 2; ++ks) {
        const float* src = qbase + (size_t)(row + x * 16) * HD + ks * 32 + kof;
        float4 v0 = *reinterpret_cast<const float4*>(src);
        float4 v1 = *reinterpret_cast<const float4*>(src + 4);
        bf16x8 f = { (bf16)v0.x, (bf16)v0.y, (bf16)v0.z, (bf16)v0.w,
                     (bf16)v1.x, (bf16)v1.y, (bf16)v1.z, (bf16)v1.w };
        a[x][ks] = f;
      }
  }

  const int m_base = (SEQ - 1) - (i0 + 63);
  const int tb = blockIdx.z * 9;
  const int te = (blockIdx.z == 0) ? 9 : 17;

  const size_t outbase = (size_t)hb << 20;

  // B-fragment base address for this thread: row (m-part) + chunk offset.
  // bb[ks][y]: row = m0 + wc*32 + y*16 + (lane&15), cols h*64 + (ks*4+(lane>>4))*8 ..+8
  const bf16* Pb0 = P + (size_t)(wc * 32 + (lane & 15)) * EMB + h * HD + (lane >> 4) * 8;

  for (int t = tb; t < te; ++t) {
    const int m0 = m_base + t * 64;
    const bf16* Pt = Pb0 + (size_t)m0 * EMB;

    f32x4 acc[2][2] = {};
    #pragma unroll
    for (int ks = 0; ks < 2; ++ks) {
      bf16x8 bb[2];
      #pragma unroll
      for (int y = 0; y < 2; ++y)
        bb[y] = *reinterpret_cast<const bf16x8*>(Pt + (size_t)y * 16 * EMB + ks * 32);
      #pragma unroll
      for (int x = 0; x < 2; ++x)
        #pragma unroll
        for (int y = 0; y < 2; ++y)
          acc[x][y] = __builtin_amdgcn_mfma_f32_16x16x32_bf16(a[x][ks], bb[y], acc[x][y], 0, 0, 0);
    }

    // ---- epilogue: shift + masked scatter (identical to R2)
    #pragma unroll
    for (int x = 0; x < 2; ++x)
      #pragma unroll
      for (int y = 0; y < 2; ++y)
        #pragma unroll
        for (int r = 0; r < 4; ++r) {
          int i = i0 + wr * 32 + x * 16 + (lane >> 4) * 4 + r;
          int m = m0 + wc * 32 + y * 16 + (lane & 15);
          int j = m - (SEQ - 1) + i;
          if ((unsigned)j < SEQ)
            out[outbase + (size_t)i * SEQ + j] = acc[x][y][r];
        }
    // no barrier, no LDS — waves stream freely into the next tile
  }
}

extern "C" void kernel_launch(void* const* d_in, const int* in_sizes, int n_in,
                              void* d_out, int out_size, void* d_ws, size_t ws_size,
                              hipStream_t stream) {
  const float* query  = (const float*)d_in[0];   // [2,16,1024,64]
  const float* posEmb = (const float*)d_in[1];   // [2047,1024]
  const float* W      = (const float*)d_in[2];   // [1024,1024]
  float* out = (float*)d_out;                    // [2,16,1024,1024]
  bf16* P = (bf16*)d_ws;                         // [2048][1024] bf16 = 4 MB

  gemm1_kernel<<<dim3(16, 32), 256, 0, stream>>>(posEmb, W, P);
  band2c_kernel<<<dim3(16, 32, 2), 256, 0, stream>>>(query, P, out);
}

// Round 9
// 64.333 us; speedup vs baseline: 6.2995x; 1.0201x over previous
//
#include <hip/hip_runtime.h>

typedef __bf16 bf16;
typedef __bf16 bf16x4 __attribute__((ext_vector_type(4)));
typedef __bf16 bf16x8 __attribute__((ext_vector_type(8)));
typedef float f32x4 __attribute__((ext_vector_type(4)));

#define SEQ 1024
#define EMB 1024
#define NH 16
#define HD 64
#define M2 2047   // 2*MAX_POS - 1

// ---------------------------------------------------------------------------
// Kernel 1 (R2 version, unchanged): P[2048][1024] (bf16) = gather(posEmb) @ W
// ---------------------------------------------------------------------------
__global__ __launch_bounds__(256) void gemm1_kernel(const float* __restrict__ posEmb,
                                                    const float* __restrict__ W,
                                                    bf16* __restrict__ P) {
  __shared__ bf16 As[64][72];
  __shared__ bf16 Bs[64][72];
  const int tid  = threadIdx.x;
  const int lane = tid & 63;
  const int wave = tid >> 6;
  const int wr = wave >> 1, wc = wave & 1;
  const int m0 = blockIdx.y * 64;
  const int n0 = blockIdx.x * 64;

  f32x4 acc[2][2] = {};

  for (int k0 = 0; k0 < EMB; k0 += 64) {
    {
      const int row = tid >> 2;
      const int c0  = (tid & 3) * 16;
      int g = m0 + row;
      if (g > M2 - 1) g = M2 - 1;
      const float4* src = reinterpret_cast<const float4*>(posEmb + (size_t)g * EMB + k0 + c0);
      #pragma unroll
      for (int i = 0; i < 4; ++i) {
        float4 v = src[i];
        bf16x4 bb = { (bf16)v.x, (bf16)v.y, (bf16)v.z, (bf16)v.w };
        *reinterpret_cast<bf16x4*>(&As[row][c0 + 4 * i]) = bb;
      }
    }
    {
      const int n  = tid & 63;
      const int kg = tid >> 6;
      #pragma unroll
      for (int u = 0; u < 4; ++u) {
        bf16x4 bb;
        #pragma unroll
        for (int e = 0; e < 4; ++e) {
          int k = kg * 16 + u * 4 + e;
          bb[e] = (bf16)W[(size_t)(k0 + k) * EMB + n0 + n];
        }
        *reinterpret_cast<bf16x4*>(&Bs[n][kg * 16 + u * 4]) = bb;
      }
    }
    __syncthreads();
    #pragma unroll
    for (int ks = 0; ks < 2; ++ks) {
      bf16x8 a[2], b[2];
      #pragma unroll
      for (int x = 0; x < 2; ++x) {
        a[x] = *reinterpret_cast<const bf16x8*>(&As[wr * 32 + x * 16 + (lane & 15)][ks * 32 + 8 * (lane >> 4)]);
        b[x] = *reinterpret_cast<const bf16x8*>(&Bs[wc * 32 + x * 16 + (lane & 15)][ks * 32 + 8 * (lane >> 4)]);
      }
      #pragma unroll
      for (int x = 0; x < 2; ++x)
        #pragma unroll
        for (int y = 0; y < 2; ++y)
          acc[x][y] = __builtin_amdgcn_mfma_f32_16x16x32_bf16(a[x], b[y], acc[x][y], 0, 0, 0);
    }
    __syncthreads();
  }

  #pragma unroll
  for (int x = 0; x < 2; ++x)
    #pragma unroll
    for (int y = 0; y < 2; ++y)
      #pragma unroll
      for (int r = 0; r < 4; ++r) {
        int row = m0 + wr * 32 + x * 16 + (lane >> 4) * 4 + r;
        int col = n0 + wc * 32 + y * 16 + (lane & 15);
        P[(size_t)row * EMB + col] = (bf16)acc[x][y][r];
      }
}

// ---------------------------------------------------------------------------
// Kernel 2 (band2d): R2 structure + counted-vmcnt barrier (true T4).
//   Per iter: [vmcnt(16) drains ONLY the 2 prefetch loads; 16 stores of the
//   previous tile stay in flight] -> s_barrier -> ds_read b-frags ->
//   STAGE(t+1) [loads OLDER than this tile's stores] -> MFMA -> stores.
//   Interior tiles t=1..15 store unconditionally (j provably in [1,1023]),
//   so the static store count (16) is exact; masked edge tiles t in {0,16}
//   are followed by a vmcnt(0) (t=0) or nothing (t=16, kernel end).
// ---------------------------------------------------------------------------
__global__ __launch_bounds__(256) void band2d_kernel(const float* __restrict__ q,
                                                     const bf16* __restrict__ P,
                                                     float* __restrict__ out) {
  __shared__ bf16 Pbuf[2][64 * 64];
  const int tid  = threadIdx.x;
  const int lane = tid & 63;
  const int wave = tid >> 6;
  const int wr = wave >> 1, wc = wave & 1;

  const int i0 = blockIdx.x * 64;
  const int hb = blockIdx.y;
  const int h  = hb >> 1;
  const int b  = hb & 1;

  // ---- Q fragments: direct global f32 -> bf16x8 registers.
  bf16x8 a[2][2];
  {
    const float* qbase = q + ((size_t)(h * (2 * SEQ) + b * SEQ)) * HD;
    const int row = i0 + wr * 32 + (lane & 15);
    const int kof = 8 * (lane >> 4);
    #pragma unroll
    for (int x = 0; x < 2; ++x)
      #pragma unroll
      for (int ks = 0; ks < 2; ++ks) {
        const float* src = qbase + (size_t)(row + x * 16) * HD + ks * 32 + kof;
        float4 v0 = *reinterpret_cast<const float4*>(src);
        float4 v1 = *reinterpret_cast<const float4*>(src + 4);
        bf16x8 f = { (bf16)v0.x, (bf16)v0.y, (bf16)v0.z, (bf16)v0.w,
                     (bf16)v1.x, (bf16)v1.y, (bf16)v1.z, (bf16)v1.w };
        a[x][ks] = f;
      }
  }

  const int m_base = (SEQ - 1) - (i0 + 63);
  const int tb = blockIdx.z * 9;                // 0 or 9
  const int te = (blockIdx.z == 0) ? 9 : 17;    // tiles [tb, te)

  auto STAGE = [&](int bi, int t) {
    const int m0 = m_base + t * 64;
    const char* Pb = reinterpret_cast<const char*>(P);
    #pragma unroll
    for (int i = 0; i < 2; ++i) {
      int s   = wave * 128 + i * 64 + lane;
      int row = s >> 3;
      int cs  = s & 7;
      int cd  = cs ^ (row & 7);
      const void* g = Pb + ((size_t)(m0 + row) * EMB + h * HD) * 2 + cd * 16;
      char* l = reinterpret_cast<char*>(&Pbuf[bi][0]) + (wave * 128 + i * 64) * 16;
      __builtin_amdgcn_global_load_lds(
          (const __attribute__((address_space(1))) void*)g,
          (__attribute__((address_space(3))) void*)l, 16, 0, 0);
    }
  };

  const size_t outbase = (size_t)hb << 20;

  STAGE(0, tb);
  asm volatile("s_waitcnt vmcnt(0)");
  __builtin_amdgcn_s_barrier();

  int cur = 0;
  for (int t = tb; t < te; ++t) {
    if (t > tb) {
      // Counted sync: drain only the 2 prefetch loads (oldest); leave the
      // previous tile's 16 stores in flight. After a masked edge tile (t==0)
      // the store count is not statically 16 -> conservative vmcnt(0).
      __builtin_amdgcn_sched_barrier(0);
      if (tb == 0 && t == 1) {
        asm volatile("s_waitcnt vmcnt(0)");
      } else {
        asm volatile("s_waitcnt vmcnt(16)");
      }
      __builtin_amdgcn_sched_barrier(0);
      __builtin_amdgcn_s_barrier();
    }

    // ---- b-fragments from Pbuf[cur] (swizzled ds_read_b128, compiler waits lgkm)
    const char* buf = reinterpret_cast<const char*>(&Pbuf[cur][0]);
    bf16x8 bb[2][2];
    #pragma unroll
    for (int ks = 0; ks < 2; ++ks)
      #pragma unroll
      for (int y = 0; y < 2; ++y) {
        int mrow  = wc * 32 + y * 16 + (lane & 15);
        int chunk = ks * 4 + (lane >> 4);
        int sw    = chunk ^ (mrow & 7);
        bb[ks][y] = *reinterpret_cast<const bf16x8*>(buf + mrow * 128 + sw * 16);
      }
    __builtin_amdgcn_sched_barrier(0);

    // ---- prefetch next tile (loads issued BEFORE this tile's stores)
    if (t + 1 < te) STAGE(cur ^ 1, t + 1);
    __builtin_amdgcn_sched_barrier(0);

    // ---- MFMA
    f32x4 acc[2][2] = {};
    #pragma unroll
    for (int ks = 0; ks < 2; ++ks)
      #pragma unroll
      for (int x = 0; x < 2; ++x)
        #pragma unroll
        for (int y = 0; y < 2; ++y)
          acc[x][y] = __builtin_amdgcn_mfma_f32_16x16x32_bf16(a[x][ks], bb[ks][y], acc[x][y], 0, 0, 0);

    // ---- stores: unconditional for interior tiles (j in [1,1023] proven)
    const int m0 = m_base + t * 64;
    const bool edge = (t == 0) || (t == 16);
    #pragma unroll
    for (int x = 0; x < 2; ++x)
      #pragma unroll
      for (int y = 0; y < 2; ++y)
        #pragma unroll
        for (int r = 0; r < 4; ++r) {
          int i = i0 + wr * 32 + x * 16 + (lane >> 4) * 4 + r;
          int m = m0 + wc * 32 + y * 16 + (lane & 15);
          int j = m - (SEQ - 1) + i;
          if (!edge || (unsigned)j < SEQ)
            out[outbase + (size_t)i * SEQ + j] = acc[x][y][r];
        }
    __builtin_amdgcn_sched_barrier(0);

    cur ^= 1;
  }
}

extern "C" void kernel_launch(void* const* d_in, const int* in_sizes, int n_in,
                              void* d_out, int out_size, void* d_ws, size_t ws_size,
                              hipStream_t stream) {
  const float* query  = (const float*)d_in[0];   // [2,16,1024,64]
  const float* posEmb = (const float*)d_in[1];   // [2047,1024]
  const float* W      = (const float*)d_in[2];   // [1024,1024]
  float* out = (float*)d_out;                    // [2,16,1024,1024]
  bf16* P = (bf16*)d_ws;                         // [2048][1024] bf16 = 4 MB

  gemm1_kernel<<<dim3(16, 32), 256, 0, stream>>>(posEmb, W, P);
  band2d_kernel<<<dim3(16, 32, 2), 256, 0, stream>>>(query, P, out);
}

// Round 10
// 63.410 us; speedup vs baseline: 6.3911x; 1.0146x over previous
//
#include <hip/hip_runtime.h>

typedef __bf16 bf16;
typedef __bf16 bf16x4 __attribute__((ext_vector_type(4)));
typedef __bf16 bf16x8 __attribute__((ext_vector_type(8)));
typedef float f32x4 __attribute__((ext_vector_type(4)));

#define SEQ 1024
#define EMB 1024
#define NH 16
#define HD 64
#define M2 2047   // 2*MAX_POS - 1

// ---------------------------------------------------------------------------
// Kernel 1 (R2 version, unchanged): P[2048][1024] (bf16) = gather(posEmb) @ W
// ---------------------------------------------------------------------------
__global__ __launch_bounds__(256) void gemm1_kernel(const float* __restrict__ posEmb,
                                                    const float* __restrict__ W,
                                                    bf16* __restrict__ P) {
  __shared__ bf16 As[64][72];
  __shared__ bf16 Bs[64][72];
  const int tid  = threadIdx.x;
  const int lane = tid & 63;
  const int wave = tid >> 6;
  const int wr = wave >> 1, wc = wave & 1;
  const int m0 = blockIdx.y * 64;
  const int n0 = blockIdx.x * 64;

  f32x4 acc[2][2] = {};

  for (int k0 = 0; k0 < EMB; k0 += 64) {
    {
      const int row = tid >> 2;
      const int c0  = (tid & 3) * 16;
      int g = m0 + row;
      if (g > M2 - 1) g = M2 - 1;
      const float4* src = reinterpret_cast<const float4*>(posEmb + (size_t)g * EMB + k0 + c0);
      #pragma unroll
      for (int i = 0; i < 4; ++i) {
        float4 v = src[i];
        bf16x4 bb = { (bf16)v.x, (bf16)v.y, (bf16)v.z, (bf16)v.w };
        *reinterpret_cast<bf16x4*>(&As[row][c0 + 4 * i]) = bb;
      }
    }
    {
      const int n  = tid & 63;
      const int kg = tid >> 6;
      #pragma unroll
      for (int u = 0; u < 4; ++u) {
        bf16x4 bb;
        #pragma unroll
        for (int e = 0; e < 4; ++e) {
          int k = kg * 16 + u * 4 + e;
          bb[e] = (bf16)W[(size_t)(k0 + k) * EMB + n0 + n];
        }
        *reinterpret_cast<bf16x4*>(&Bs[n][kg * 16 + u * 4]) = bb;
      }
    }
    __syncthreads();
    #pragma unroll
    for (int ks = 0; ks < 2; ++ks) {
      bf16x8 a[2], b[2];
      #pragma unroll
      for (int x = 0; x < 2; ++x) {
        a[x] = *reinterpret_cast<const bf16x8*>(&As[wr * 32 + x * 16 + (lane & 15)][ks * 32 + 8 * (lane >> 4)]);
        b[x] = *reinterpret_cast<const bf16x8*>(&Bs[wc * 32 + x * 16 + (lane & 15)][ks * 32 + 8 * (lane >> 4)]);
      }
      #pragma unroll
      for (int x = 0; x < 2; ++x)
        #pragma unroll
        for (int y = 0; y < 2; ++y)
          acc[x][y] = __builtin_amdgcn_mfma_f32_16x16x32_bf16(a[x], b[y], acc[x][y], 0, 0, 0);
    }
    __syncthreads();
  }

  #pragma unroll
  for (int x = 0; x < 2; ++x)
    #pragma unroll
    for (int y = 0; y < 2; ++y)
      #pragma unroll
      for (int r = 0; r < 4; ++r) {
        int row = m0 + wr * 32 + x * 16 + (lane >> 4) * 4 + r;
        int col = n0 + wc * 32 + y * 16 + (lane & 15);
        P[(size_t)row * EMB + col] = (bf16)acc[x][y][r];
      }
}

// ---------------------------------------------------------------------------
// Kernel 2 (band2e): EXACT R2 band2 structure, but the 17-tile m-range is
//   split 4 ways (z in 0..3) instead of 2: grid = 2048 blocks = 8 blocks/CU
//   = 32 waves/CU (full wave capacity; was 16). Pure TLP change — the only
//   edit vs R2 is tb/te. Q re-reads (4x) are L2/L3 hits.
// ---------------------------------------------------------------------------
__global__ __launch_bounds__(256) void band2e_kernel(const float* __restrict__ q,
                                                     const bf16* __restrict__ P,
                                                     float* __restrict__ out) {
  __shared__ bf16 Pbuf[2][64 * 64];
  const int tid  = threadIdx.x;
  const int lane = tid & 63;
  const int wave = tid >> 6;
  const int wr = wave >> 1, wc = wave & 1;

  const int i0 = blockIdx.x * 64;
  const int hb = blockIdx.y;
  const int h  = hb >> 1;
  const int b  = hb & 1;

  bf16x8 a[2][2];
  {
    const float* qbase = q + ((size_t)(h * (2 * SEQ) + b * SEQ)) * HD;
    const int row = i0 + wr * 32 + (lane & 15);
    const int kof = 8 * (lane >> 4);
    #pragma unroll
    for (int x = 0; x < 2; ++x)
      #pragma unroll
      for (int ks = 0; ks < 2; ++ks) {
        const float* src = qbase + (size_t)(row + x * 16) * HD + ks * 32 + kof;
        float4 v0 = *reinterpret_cast<const float4*>(src);
        float4 v1 = *reinterpret_cast<const float4*>(src + 4);
        bf16x8 f = { (bf16)v0.x, (bf16)v0.y, (bf16)v0.z, (bf16)v0.w,
                     (bf16)v1.x, (bf16)v1.y, (bf16)v1.z, (bf16)v1.w };
        a[x][ks] = f;
      }
  }

  const int m_base = (SEQ - 1) - (i0 + 63);
  const int z  = blockIdx.z;                    // 0..3
  const int tb = (z == 0) ? 0 : 4 * z + 1;      // 0,5,9,13
  const int te = 4 * z + 5;                     // 5,9,13,17

  auto STAGE = [&](int bi, int t) {
    const int m0 = m_base + t * 64;
    const char* Pb = reinterpret_cast<const char*>(P);
    #pragma unroll
    for (int i = 0; i < 2; ++i) {
      int s   = wave * 128 + i * 64 + lane;
      int row = s >> 3;
      int cs  = s & 7;
      int cd  = cs ^ (row & 7);
      const void* g = Pb + ((size_t)(m0 + row) * EMB + h * HD) * 2 + cd * 16;
      char* l = reinterpret_cast<char*>(&Pbuf[bi][0]) + (wave * 128 + i * 64) * 16;
      __builtin_amdgcn_global_load_lds(
          (const __attribute__((address_space(1))) void*)g,
          (__attribute__((address_space(3))) void*)l, 16, 0, 0);
    }
  };

  const size_t outbase = (size_t)hb << 20;

  STAGE(0, tb);
  __syncthreads();

  int cur = 0;
  for (int t = tb; t < te; ++t) {
    if (t + 1 < te) STAGE(cur ^ 1, t + 1);

    const char* buf = reinterpret_cast<const char*>(&Pbuf[cur][0]);
    f32x4 acc[2][2] = {};
    #pragma unroll
    for (int ks = 0; ks < 2; ++ks) {
      bf16x8 bb[2];
      #pragma unroll
      for (int y = 0; y < 2; ++y) {
        int mrow  = wc * 32 + y * 16 + (lane & 15);
        int chunk = ks * 4 + (lane >> 4);
        int sw    = chunk ^ (mrow & 7);
        bb[y] = *reinterpret_cast<const bf16x8*>(buf + mrow * 128 + sw * 16);
      }
      #pragma unroll
      for (int x = 0; x < 2; ++x)
        #pragma unroll
        for (int y = 0; y < 2; ++y)
          acc[x][y] = __builtin_amdgcn_mfma_f32_16x16x32_bf16(a[x][ks], bb[y], acc[x][y], 0, 0, 0);
    }

    const int m0 = m_base + t * 64;
    #pragma unroll
    for (int x = 0; x < 2; ++x)
      #pragma unroll
      for (int y = 0; y < 2; ++y)
        #pragma unroll
        for (int r = 0; r < 4; ++r) {
          int i = i0 + wr * 32 + x * 16 + (lane >> 4) * 4 + r;
          int m = m0 + wc * 32 + y * 16 + (lane & 15);
          int j = m - (SEQ - 1) + i;
          if ((unsigned)j < SEQ)
            out[outbase + (size_t)i * SEQ + j] = acc[x][y][r];
        }

    __syncthreads();
    cur ^= 1;
  }
}

extern "C" void kernel_launch(void* const* d_in, const int* in_sizes, int n_in,
                              void* d_out, int out_size, void* d_ws, size_t ws_size,
                              hipStream_t stream) {
  const float* query  = (const float*)d_in[0];   // [2,16,1024,64]
  const float* posEmb = (const float*)d_in[1];   // [2047,1024]
  const float* W      = (const float*)d_in[2];   // [1024,1024]
  float* out = (float*)d_out;                    // [2,16,1024,1024]
  bf16* P = (bf16*)d_ws;                         // [2048][1024] bf16 = 4 MB

  gemm1_kernel<<<dim3(16, 32), 256, 0, stream>>>(posEmb, W, P);
  band2e_kernel<<<dim3(16, 32, 4), 256, 0, stream>>>(query, P, out);
}